// Round 7
// baseline (267.020 us; speedup 1.0000x reference)
//
#include <hip/hip_runtime.h>
#include <stdint.h>

// ---- problem constants ----
#define D_MODEL 1024
#define NH 16
#define DK 64
#define BBATCH 2
#define LL 2048
#define SCALE_LOG2E 0.1803368801111244f   // 0.125 * log2(e), folded into Wq staging convert

typedef unsigned short bfu;  // bf16 storage as raw bits
typedef __attribute__((ext_vector_type(8))) short bf16x8;  // MFMA A/B frag (8 bf16)
typedef __attribute__((ext_vector_type(4))) float f32x4;   // MFMA C/D frag

union BF8 { uint32_t w[4]; bf16x8 v; };

__device__ __forceinline__ bfu f2bf(float f) {
    union { float f; uint32_t u; } a; a.f = f;
    uint32_t r = a.u + 0x7FFF + ((a.u >> 16) & 1);   // RNE
    return (bfu)(r >> 16);
}
// pack two floats' high halves (truncating bf16) into one u32: (hi.bf16<<16)|lo.bf16
__device__ __forceinline__ uint32_t pktrunc(float hi, float lo) {
    return __builtin_amdgcn_perm(__float_as_uint(hi), __float_as_uint(lo), 0x07060302);
}

// async global->LDS, 16B per lane; LDS dest = wave-uniform base + lane*16
__device__ __forceinline__ void gload_lds16(const void* g, void* l) {
    __builtin_amdgcn_global_load_lds(
        (const __attribute__((address_space(1))) void*)g,
        (__attribute__((address_space(3))) void*)l, 16, 0, 0);
}

// XOR-swizzled LDS addressing for 64-elem rows (8 chunks of 8 bf16 / 16 B):
//   staging at linear chunk c (row r=c>>3, pos x=c&7) pulls GLOBAL chunk x^(r&7)
//   read of (row R, global chunk G) -> LDS element offset R*64 + ((G^(R&7))<<3)
// => every quad's 16 lanes spread over all 32 banks at 2 lanes/bank (free, m136).
__device__ __forceinline__ int swz(int R, int G) {
    return R * 64 + (((G ^ (R & 7))) << 3);
}

// load 8 fp32 from g, truncate to bf16, return packed 16B
__device__ __forceinline__ uint4 ld8_f32_to_bf16(const float* g, float sc) {
    const float4* s = (const float4*)g;
    float4 u = s[0], v = s[1];
    u.x *= sc; u.y *= sc; u.z *= sc; u.w *= sc;
    v.x *= sc; v.y *= sc; v.z *= sc; v.w *= sc;
    uint4 w;
    w.x = pktrunc(u.y, u.x); w.y = pktrunc(u.w, u.z);
    w.z = pktrunc(v.y, v.x); w.w = pktrunc(v.w, v.z);
    return w;
}

// ---------------- projection GEMM: fp32 in, bf16 MFMA, conversion fused into staging ----
#define BM 128
#define BN 128
#define BKK 64

// k-permutation pi for the S^T->B-frag register repack (applied to V columns at store):
// l = [b5 b4 b3 b2 b1 b0] -> stored position [b4 b3 b2 b5 b1 b0]  (verified round 3)
__device__ __forceinline__ int kperm(int k) {
    return (((k >> 4) & 1) << 5) | (((k >> 2) & 3) << 3) | (((k >> 5) & 1) << 2) | (k & 3);
}

// grid: 768 blocks 1D. XCD r = id&7 owns zy-tiles [12r, 12r+12), all 8 x-tiles of each
// zy on the SAME XCD -> fp32 A row-tile fetched from HBM into exactly one XCD's L2.
__global__ __launch_bounds__(256, 2) void gemm_proj(
    const float* __restrict__ Qf, const float* __restrict__ Kf, const float* __restrict__ Vf,
    const float* __restrict__ Wqf, const float* __restrict__ Wkf, const float* __restrict__ Wvf,
    const float* __restrict__ bq, const float* __restrict__ bk, const float* __restrict__ bv,
    bfu* __restrict__ qp, bfu* __restrict__ kp, bfu* __restrict__ vt)
{
    const int id = blockIdx.x;
    const int xcd = id & 7, q = id >> 3;        // q in [0,96)
    const int zy = xcd * 12 + (q >> 3);         // 12 zy-tiles per XCD
    const int x  = q & 7;
    const int z  = zy >> 5, y = zy & 31;

    const float* A = (z == 0) ? Qf : ((z == 1) ? Kf : Vf);
    const float* B = (z == 0) ? Wqf : ((z == 1) ? Wkf : Wvf);
    const float* bias = (z == 0) ? bq : ((z == 1) ? bk : bv);
    const float bsc = (z == 0) ? SCALE_LOG2E : 1.0f;
    bfu* out = (z == 0) ? qp : ((z == 1) ? kp : vt);

    __shared__ __align__(16) bfu As[BM * BKK];
    __shared__ __align__(16) bfu Bs[BN * BKK];

    const int t = threadIdx.x;
    const int lane = t & 63;
    const int wave = t >> 6;
    const int wm = wave & 1, wn = wave >> 1;
    const int tm = y * BM, tn = x * BN;
    const int lr = lane & 15, quad = lane >> 4;

    f32x4 acc[4][4];
    for (int i = 0; i < 4; i++) for (int j = 0; j < 4; j++) acc[i][j] = (f32x4){0.f, 0.f, 0.f, 0.f};

    for (int kt = 0; kt < 1024; kt += BKK) {
        // fp32 -> bf16 register-convert staging (trunc), XOR-swizzled
        for (int it = 0; it < 4; ++it) {
            int c = t + it * 256;
            int row = c >> 3, gx = (c & 7) ^ (row & 7);
            uint4 w = ld8_f32_to_bf16(&A[(size_t)(tm + row) * 1024 + kt + gx * 8], 1.0f);
            *(uint4*)&As[(size_t)c * 8] = w;
        }
        for (int it = 0; it < 4; ++it) {
            int c = t + it * 256;
            int row = c >> 3, gx = (c & 7) ^ (row & 7);
            uint4 w = ld8_f32_to_bf16(&B[(size_t)(tn + row) * 1024 + kt + gx * 8], bsc);
            *(uint4*)&Bs[(size_t)c * 8] = w;
        }
        __syncthreads();
        for (int kx = 0; kx < 2; kx++) {
            bf16x8 a[4], b[4];
            for (int i = 0; i < 4; i++)
                a[i] = *(const bf16x8*)&As[swz(wm * 64 + i * 16 + lr, kx * 4 + quad)];
            for (int i = 0; i < 4; i++)
                b[i] = *(const bf16x8*)&Bs[swz(wn * 64 + i * 16 + lr, kx * 4 + quad)];
            for (int mt = 0; mt < 4; mt++)
                for (int nt = 0; nt < 4; nt++)
                    acc[mt][nt] = __builtin_amdgcn_mfma_f32_16x16x32_bf16(a[mt], b[nt], acc[mt][nt], 0, 0, 0);
        }
        __syncthreads();
    }

    for (int mt = 0; mt < 4; mt++)
        for (int nt = 0; nt < 4; nt++)
            for (int r = 0; r < 4; r++) {
                int m = tm + wm * 64 + mt * 16 + quad * 4 + r;   // row of C
                int n = tn + wn * 64 + nt * 16 + lr;             // col of C
                float v = acc[mt][nt][r] + bias[n] * bsc;
                int b_ = m >> 11, l = m & 2047;
                int h = n >> 6, d = n & 63;
                if (z < 2)
                    out[((size_t)((b_ * NH + h) * LL + l)) * DK + d] = f2bf(v);
                else {
                    int lp = (l & ~63) | kperm(l & 63);          // pi-permuted columns
                    out[((size_t)((b_ * NH + h) * DK + d)) * LL + lp] = f2bf(v);
                }
            }
}

// ---------------- flash attention v5 (reverted round-5 version): in-block j-split ----------------
// 1024 blocks x 256 threads (4 waves). Block = (bh, 64-row band).
// Wave w: hw=w&1 -> rows [hw*32, hw*32+32); jh=w>>1 -> j-half.
// jh=0 handles j in [0,n0), jh=1 handles j in [n0,n), n=band+1, n0=ceil(n/2).
// Lockstep loop over i in [0,n0); each half stages its own K/V double-buffer.
// No running max (round-3 invariant) -> partial (O,l) are pure sums -> halves
// combine associatively through LDS after the loop.
__global__ __launch_bounds__(256, 2) void attn_kernel(
    const bfu* __restrict__ qp, const bfu* __restrict__ kp, const bfu* __restrict__ vtp,
    bfu* __restrict__ attn)
{
    const int id = blockIdx.x;
    const int bh = (id & 7) | (((id >> 3) & 3) << 3);   // id%8 == bh%8 -> per-bh XCD affinity
    const int band = 31 - (id >> 5);                    // LPT: heavy bands first
    const int b_ = bh >> 4, h = bh & 15;
    const int t = threadIdx.x;
    const int lane = t & 63, w = t >> 6;
    const int hw = w & 1;          // row half
    const int jh = w >> 1;         // j half (== t>>7, same partition as staging group)
    const int lr = lane & 15, quad = lane >> 4, q8 = quad << 3;

    __shared__ __align__(16) bfu Ks[2][2][64 * 64];   // [jh][buf] 32 KB
    __shared__ __align__(16) bfu Vs[2][2][64 * 64];   // [jh][buf] 32 KB

    const int n  = band + 1;
    const int n0 = (n + 1) >> 1;
    const int nj = (jh == 0) ? n0 : (n - n0);   // my half's iteration count
    const int jb = (jh == 0) ? 0 : n0;          // my half's base j-tile

    const int tl = t & 127;                      // staging lane within half-group
    const int r0 = band * 64 + hw * 32;

    const bfu* kbase = kp + (size_t)bh * LL * DK;
    const bfu* vbase = vtp + (size_t)bh * DK * LL;

    // Q B-frags (pre-scaled by 0.125*log2e via Wq): n=lr -> Q row, k = quad*8+j -> d
    bf16x8 aq[2][2];
    for (int mt = 0; mt < 2; mt++)
        for (int kx = 0; kx < 2; kx++)
            aq[mt][kx] = *(const bf16x8*)&qp[((size_t)bh * LL + r0 + mt * 16 + lr) * DK + kx * 32 + q8];

    f32x4 o[2][4];
    for (int mt = 0; mt < 2; mt++)
        for (int nf = 0; nf < 4; nf++) o[mt][nf] = (f32x4){0.f, 0.f, 0.f, 0.f};
    float lsum[2] = {0.f, 0.f};

    // prologue: each half-group stages its first tile (jh=1 may have none)
    if (nj > 0) {
        for (int it = 0; it < 4; ++it) {
            int c = tl + it * 128;
            int r = c >> 3, gx = (c & 7) ^ (r & 7);
            gload_lds16(&kbase[(size_t)(jb * 64 + r) * DK + gx * 8], &Ks[jh][0][(size_t)c * 8]);
            gload_lds16(&vbase[(size_t)r * LL + jb * 64 + gx * 8], &Vs[jh][0][(size_t)c * 8]);
        }
    }
    __syncthreads();

    for (int i = 0; i < n0; ++i) {
        const int buf = i & 1;
        if (i + 1 < nj) {   // prefetch my half's next tile (drained at barrier)
            const int nb = buf ^ 1, jn = jb + i + 1;
            for (int it = 0; it < 4; ++it) {
                int c = tl + it * 128;
                int r = c >> 3, gx = (c & 7) ^ (r & 7);
                gload_lds16(&kbase[(size_t)(jn * 64 + r) * DK + gx * 8], &Ks[jh][nb][(size_t)c * 8]);
                gload_lds16(&vbase[(size_t)r * LL + jn * 64 + gx * 8], &Vs[jh][nb][(size_t)c * 8]);
            }
        }
        if (i < nj) {
            const int j = jb + i;
            const bfu* Kt = Ks[jh][buf];
            const bfu* Vt = Vs[jh][buf];
            // --- S^T = K Q^T : A=K-frag (rows=k), B=Q-frag (cols=m) ---
            f32x4 sv[4][2];   // [kt][mt]
            for (int kt = 0; kt < 4; kt++)
                for (int mt = 0; mt < 2; mt++) sv[kt][mt] = (f32x4){0.f, 0.f, 0.f, 0.f};
            for (int kx = 0; kx < 2; kx++)
                for (int kt = 0; kt < 4; kt++) {
                    bf16x8 ak = *(const bf16x8*)&Kt[swz(kt * 16 + lr, kx * 4 + quad)];
                    for (int mt = 0; mt < 2; mt++)
                        sv[kt][mt] = __builtin_amdgcn_mfma_f32_16x16x32_bf16(ak, aq[mt][kx], sv[kt][mt], 0, 0, 0);
                }
            // --- causal mask on the diagonal tile: valid iff k <= m ---
            if (j == band) {
                const int mb = r0 & 63;
                for (int kt = 0; kt < 4; kt++)
                    for (int mt = 0; mt < 2; mt++)
                        for (int r = 0; r < 4; r++) {
                            int kl = kt * 16 + quad * 4 + r;
                            int ml = mb + mt * 16 + lr;
                            if (kl > ml) sv[kt][mt][r] = -1e9f;
                        }
            }
            // --- p = exp2(s), per-lane partial l ---
            for (int kt = 0; kt < 4; kt++)
                for (int mt = 0; mt < 2; mt++)
                    for (int r = 0; r < 4; r++) {
                        float e = __builtin_amdgcn_exp2f(sv[kt][mt][r]);
                        sv[kt][mt][r] = e;
                        lsum[mt] += e;
                    }
            // --- O^T += V^T P^T : A=V-frag (pi-permuted cols), B=P-frag from registers ---
            for (int kx = 0; kx < 2; kx++) {
                BF8 pf[2];
                for (int mt = 0; mt < 2; mt++) {
                    pf[mt].w[0] = pktrunc(sv[kx][mt][1], sv[kx][mt][0]);
                    pf[mt].w[1] = pktrunc(sv[kx][mt][3], sv[kx][mt][2]);
                    pf[mt].w[2] = pktrunc(sv[2 + kx][mt][1], sv[2 + kx][mt][0]);
                    pf[mt].w[3] = pktrunc(sv[2 + kx][mt][3], sv[2 + kx][mt][2]);
                }
                for (int nf = 0; nf < 4; nf++) {
                    bf16x8 av = *(const bf16x8*)&Vt[swz(nf * 16 + lr, kx * 4 + quad)];
                    for (int mt = 0; mt < 2; mt++)
                        o[mt][nf] = __builtin_amdgcn_mfma_f32_16x16x32_bf16(av, pf[mt].v, o[mt][nf], 0, 0, 0);
                }
            }
        }
        __syncthreads();   // drains prefetch + protects buffer reuse
    }

    // ---- combine the two j-halves through LDS (overlaying Ks/Vs; loop ended with barrier) ----
    float* Of = (float*)&Ks[0][0][0];   // 128 rows x 33 floats (stride 33 kills pow2 banks)
    float* Lf = (float*)&Vs[0][0][0];   // 128 x 2 floats
    const int ci = hw * 64 + lane;
    if (jh == 1) {
        float* dst = Of + ci * 33;
        for (int mt = 0; mt < 2; mt++)
            for (int nf = 0; nf < 4; nf++)
                for (int r = 0; r < 4; r++)
                    dst[mt * 16 + nf * 4 + r] = o[mt][nf][r];
        Lf[ci * 2 + 0] = lsum[0];
        Lf[ci * 2 + 1] = lsum[1];
    }
    __syncthreads();
    if (jh == 0) {
        const float* src = Of + ci * 33;
        for (int mt = 0; mt < 2; mt++)
            for (int nf = 0; nf < 4; nf++)
                for (int r = 0; r < 4; r++)
                    o[mt][nf][r] += src[mt * 16 + nf * 4 + r];
        lsum[0] += Lf[ci * 2 + 0];
        lsum[1] += Lf[ci * 2 + 1];

        // epilogue: l = quad-reduce(lsum); O^T cols = m = lr matches l's lane ownership
        for (int mt = 0; mt < 2; mt++) {
            float l = lsum[mt];
            l += __shfl_xor(l, 16);
            l += __shfl_xor(l, 32);
            float rinv = 1.0f / l;
            for (int nf = 0; nf < 4; nf++) {
                uint32_t w0 = ((uint32_t)f2bf(o[mt][nf][1] * rinv) << 16) | f2bf(o[mt][nf][0] * rinv);
                uint32_t w1 = ((uint32_t)f2bf(o[mt][nf][3] * rinv) << 16) | f2bf(o[mt][nf][2] * rinv);
                uint2 pk2 = {w0, w1};
                // attn[b, l=r0+mt*16+lr, h*64 + nf*16 + quad*4 + {0..3}]
                *(uint2*)&attn[((size_t)(b_ * LL + r0 + mt * 16 + lr)) * D_MODEL + h * DK + nf * 16 + quad * 4] = pk2;
            }
        }
    }
}

// ---------------- output GEMM: attn bf16 (gload_lds) x Wo fp32 (register-convert) ----------------
#define OBM 128
#define OBN 64

__global__ __launch_bounds__(256) void gemm_out(
    const bfu* __restrict__ A, const float* __restrict__ B,
    const float* __restrict__ bias, float* __restrict__ out)
{
    __shared__ __align__(16) bfu As[OBM * 64];   // 16 KB
    __shared__ __align__(16) bfu Bs[OBN * 64];   // 8 KB

    const int t = threadIdx.x;
    const int lane = t & 63, w = t >> 6;
    const int tm = blockIdx.y * OBM, tn = blockIdx.x * OBN;
    const int lr = lane & 15, quad = lane >> 4;

    f32x4 acc[2][4];
    for (int i = 0; i < 2; i++) for (int j = 0; j < 4; j++) acc[i][j] = (f32x4){0.f, 0.f, 0.f, 0.f};

    for (int kt = 0; kt < 1024; kt += 64) {
        for (int it = 0; it < 4; ++it) {
            int c = t + it * 256;
            int row = c >> 3, gx = (c & 7) ^ (row & 7);
            gload_lds16(&A[(size_t)(tm + row) * 1024 + kt + gx * 8], &As[(size_t)c * 8]);
        }
        for (int it = 0; it < 2; ++it) {
            int c = t + it * 256;
            int row = c >> 3, gx = (c & 7) ^ (row & 7);
            uint4 wv = ld8_f32_to_bf16(&B[(size_t)(tn + row) * 1024 + kt + gx * 8], 1.0f);
            *(uint4*)&Bs[(size_t)c * 8] = wv;
        }
        __syncthreads();
        for (int kx = 0; kx < 2; kx++) {
            bf16x8 a[2], b[4];
            for (int mt = 0; mt < 2; mt++)
                a[mt] = *(const bf16x8*)&As[swz(w * 32 + mt * 16 + lr, kx * 4 + quad)];
            for (int nt = 0; nt < 4; nt++)
                b[nt] = *(const bf16x8*)&Bs[swz(nt * 16 + lr, kx * 4 + quad)];
            for (int mt = 0; mt < 2; mt++)
                for (int nt = 0; nt < 4; nt++)
                    acc[mt][nt] = __builtin_amdgcn_mfma_f32_16x16x32_bf16(a[mt], b[nt], acc[mt][nt], 0, 0, 0);
        }
        __syncthreads();
    }

    for (int mt = 0; mt < 2; mt++)
        for (int nt = 0; nt < 4; nt++)
            for (int r = 0; r < 4; r++) {
                int m = tm + w * 32 + mt * 16 + quad * 4 + r;
                int n = tn + nt * 16 + lr;
                out[(size_t)m * D_MODEL + n] = acc[mt][nt][r] + bias[n];
            }
}

// ---------------- launch (3 kernels; cvt fused into the GEMM staging) ----------------
extern "C" void kernel_launch(void* const* d_in, const int* in_sizes, int n_in,
                              void* d_out, int out_size, void* d_ws, size_t ws_size,
                              hipStream_t stream) {
    const float* Q  = (const float*)d_in[0];
    const float* K  = (const float*)d_in[1];
    const float* V  = (const float*)d_in[2];
    // d_in[3] = causal mask (tril) — hardcoded in attn_kernel
    const float* Wq = (const float*)d_in[4];
    const float* bq = (const float*)d_in[5];
    const float* Wk = (const float*)d_in[6];
    const float* bk = (const float*)d_in[7];
    const float* Wv = (const float*)d_in[8];
    const float* bv = (const float*)d_in[9];
    const float* Wo = (const float*)d_in[10];
    const float* bo = (const float*)d_in[11];
    float* out = (float*)d_out;

    char* ws = (char*)d_ws;
    bfu* qp  = (bfu*)(ws + ((size_t)0  << 20));  // 8 MB [B,NH,L,DK]  (Wq pre-scaled)
    bfu* kp  = (bfu*)(ws + ((size_t)8  << 20));  // 8 MB [B,NH,L,DK]
    bfu* vt  = (bfu*)(ws + ((size_t)16 << 20));  // 8 MB [B,NH,DK,L] pi-permuted columns
    bfu* attn = (bfu*)(ws + ((size_t)24 << 20)); // 8 MB [B,L,D]

    gemm_proj<<<768, 256, 0, stream>>>(Q, K, V, Wq, Wk, Wv,
                                       bq, bk, bv, qp, kp, vt);

    attn_kernel<<<dim3(1024), 256, 0, stream>>>(qp, kp, vt, attn);

    gemm_out<<<dim3(16, 32), 256, 0, stream>>>(attn, Wo, bo, out);
}

// Round 8
// 232.872 us; speedup vs baseline: 1.1466x; 1.1466x over previous
//
#include <hip/hip_runtime.h>
#include <stdint.h>

// ---- problem constants ----
#define D_MODEL 1024
#define NH 16
#define DK 64
#define BBATCH 2
#define LL 2048
#define SCALE_LOG2E 0.1803368801111244f   // 0.125 * log2(e), folded into Wq staging convert

typedef unsigned short bfu;  // bf16 storage as raw bits
typedef __attribute__((ext_vector_type(8))) short bf16x8;  // MFMA A/B frag (8 bf16)
typedef __attribute__((ext_vector_type(4))) float f32x4;   // MFMA C/D frag

union BF8 { uint32_t w[4]; bf16x8 v; };

__device__ __forceinline__ bfu f2bf(float f) {
    union { float f; uint32_t u; } a; a.f = f;
    uint32_t r = a.u + 0x7FFF + ((a.u >> 16) & 1);   // RNE
    return (bfu)(r >> 16);
}
// pack two floats' high halves (truncating bf16) into one u32: (hi.bf16<<16)|lo.bf16
__device__ __forceinline__ uint32_t pktrunc(float hi, float lo) {
    return __builtin_amdgcn_perm(__float_as_uint(hi), __float_as_uint(lo), 0x07060302);
}
// pack 8 fp32 (2 float4) -> 16B of bf16 (trunc), with scale
__device__ __forceinline__ uint4 pack8(float4 u, float4 v, float sc) {
    u.x *= sc; u.y *= sc; u.z *= sc; u.w *= sc;
    v.x *= sc; v.y *= sc; v.z *= sc; v.w *= sc;
    uint4 w;
    w.x = pktrunc(u.y, u.x); w.y = pktrunc(u.w, u.z);
    w.z = pktrunc(v.y, v.x); w.w = pktrunc(v.w, v.z);
    return w;
}

// async global->LDS, 16B per lane; LDS dest = wave-uniform base + lane*16
__device__ __forceinline__ void gload_lds16(const void* g, void* l) {
    __builtin_amdgcn_global_load_lds(
        (const __attribute__((address_space(1))) void*)g,
        (__attribute__((address_space(3))) void*)l, 16, 0, 0);
}

// XOR-swizzled LDS addressing for 64-elem rows (8 chunks of 8 bf16 / 16 B):
//   staging at linear chunk c (row r=c>>3, pos x=c&7) pulls GLOBAL chunk x^(r&7)
//   read of (row R, global chunk G) -> LDS element offset R*64 + ((G^(R&7))<<3)
// => every quad's 16 lanes spread over all 32 banks at 2 lanes/bank (free, m136).
__device__ __forceinline__ int swz(int R, int G) {
    return R * 64 + (((G ^ (R & 7))) << 3);
}

// ---------------- projection GEMM: fp32 in, fused convert, REGISTER-PIPELINED staging ----
#define BM 128
#define BN 128
#define BKK 64

// k-permutation pi for the S^T->B-frag register repack (applied to V columns at store):
// l = [b5 b4 b3 b2 b1 b0] -> stored position [b4 b3 b2 b5 b1 b0]  (verified round 3)
__device__ __forceinline__ int kperm(int k) {
    return (((k >> 4) & 1) << 5) | (((k >> 2) & 3) << 3) | (((k >> 5) & 1) << 2) | (k & 3);
}

// grid: 768 blocks 1D. XCD r = id&7 owns zy-tiles [12r, 12r+12), all 8 x-tiles of each
// zy on the SAME XCD -> fp32 A row-tile fetched from HBM into exactly one XCD's L2.
// Staging pipeline: fp32 tile k+1 loaded into VGPRs while MFMA chews tile k; the
// vmcnt wait for those loads lands AFTER the MFMA phase (round-7 had it before).
__global__ __launch_bounds__(256, 2) void gemm_proj(
    const float* __restrict__ Qf, const float* __restrict__ Kf, const float* __restrict__ Vf,
    const float* __restrict__ Wqf, const float* __restrict__ Wkf, const float* __restrict__ Wvf,
    const float* __restrict__ bq, const float* __restrict__ bk, const float* __restrict__ bv,
    bfu* __restrict__ qp, bfu* __restrict__ kp, bfu* __restrict__ vt)
{
    const int id = blockIdx.x;
    const int xcd = id & 7, q = id >> 3;        // q in [0,96)
    const int zy = xcd * 12 + (q >> 3);         // 12 zy-tiles per XCD
    const int x  = q & 7;
    const int z  = zy >> 5, y = zy & 31;

    const float* A = (z == 0) ? Qf : ((z == 1) ? Kf : Vf);
    const float* B = (z == 0) ? Wqf : ((z == 1) ? Wkf : Wvf);
    const float* bias = (z == 0) ? bq : ((z == 1) ? bk : bv);
    const float bsc = (z == 0) ? SCALE_LOG2E : 1.0f;
    bfu* out = (z == 0) ? qp : ((z == 1) ? kp : vt);

    __shared__ __align__(16) bfu As[BM * BKK];
    __shared__ __align__(16) bfu Bs[BN * BKK];

    const int t = threadIdx.x;
    const int lane = t & 63;
    const int wave = t >> 6;
    const int wm = wave & 1, wn = wave >> 1;
    const int tm = y * BM, tn = x * BN;
    const int lr = lane & 15, quad = lane >> 4;

    // per-thread staging addresses (row, swizzled chunk) for 4 chunks of A and B
    int arow[4], acol[4];
    for (int it = 0; it < 4; ++it) {
        int c = t + it * 256;
        arow[it] = c >> 3;
        acol[it] = ((c & 7) ^ ((c >> 3) & 7)) * 8;
    }

    f32x4 acc[4][4];
    for (int i = 0; i < 4; i++) for (int j = 0; j < 4; j++) acc[i][j] = (f32x4){0.f, 0.f, 0.f, 0.f};

    // register double-buffer: fp32 values of the CURRENT tile
    float4 ra[4][2], rb[4][2];
    for (int it = 0; it < 4; ++it) {
        const float4* pa = (const float4*)&A[(size_t)(tm + arow[it]) * 1024 + 0 + acol[it]];
        ra[it][0] = pa[0]; ra[it][1] = pa[1];
        const float4* pb = (const float4*)&B[(size_t)(tn + arow[it]) * 1024 + 0 + acol[it]];
        rb[it][0] = pb[0]; rb[it][1] = pb[1];
    }

    for (int kt = 0; kt < 1024; kt += BKK) {
        if (kt) __syncthreads();            // prior MFMA done reading LDS before overwrite
        // convert current regs -> LDS (1 v_perm per 2 elems, ds_write_b128)
        for (int it = 0; it < 4; ++it) {
            int c = t + it * 256;
            *(uint4*)&As[(size_t)c * 8] = pack8(ra[it][0], ra[it][1], 1.0f);
            *(uint4*)&Bs[(size_t)c * 8] = pack8(rb[it][0], rb[it][1], bsc);
        }
        // issue loads for NEXT tile; their wait lands after the MFMA phase below
        if (kt + BKK < 1024) {
            for (int it = 0; it < 4; ++it) {
                const float4* pa = (const float4*)&A[(size_t)(tm + arow[it]) * 1024 + kt + BKK + acol[it]];
                ra[it][0] = pa[0]; ra[it][1] = pa[1];
                const float4* pb = (const float4*)&B[(size_t)(tn + arow[it]) * 1024 + kt + BKK + acol[it]];
                rb[it][0] = pb[0]; rb[it][1] = pb[1];
            }
        }
        __syncthreads();                    // LDS tile visible to all waves
        for (int kx = 0; kx < 2; kx++) {
            bf16x8 a[4], b[4];
            for (int i = 0; i < 4; i++)
                a[i] = *(const bf16x8*)&As[swz(wm * 64 + i * 16 + lr, kx * 4 + quad)];
            for (int i = 0; i < 4; i++)
                b[i] = *(const bf16x8*)&Bs[swz(wn * 64 + i * 16 + lr, kx * 4 + quad)];
            for (int mt = 0; mt < 4; mt++)
                for (int nt = 0; nt < 4; nt++)
                    acc[mt][nt] = __builtin_amdgcn_mfma_f32_16x16x32_bf16(a[mt], b[nt], acc[mt][nt], 0, 0, 0);
        }
    }

    for (int mt = 0; mt < 4; mt++)
        for (int nt = 0; nt < 4; nt++)
            for (int r = 0; r < 4; r++) {
                int m = tm + wm * 64 + mt * 16 + quad * 4 + r;   // row of C
                int n = tn + wn * 64 + nt * 16 + lr;             // col of C
                float v = acc[mt][nt][r] + bias[n] * bsc;
                int b_ = m >> 11, l = m & 2047;
                int h = n >> 6, d = n & 63;
                if (z < 2)
                    out[((size_t)((b_ * NH + h) * LL + l)) * DK + d] = f2bf(v);
                else {
                    int lp = (l & ~63) | kperm(l & 63);          // pi-permuted columns
                    out[((size_t)((b_ * NH + h) * DK + d)) * LL + lp] = f2bf(v);
                }
            }
}

// ---------------- flash attention v5 (round-5 version, best known): in-block j-split ----------------
__global__ __launch_bounds__(256, 2) void attn_kernel(
    const bfu* __restrict__ qp, const bfu* __restrict__ kp, const bfu* __restrict__ vtp,
    bfu* __restrict__ attn)
{
    const int id = blockIdx.x;
    const int bh = (id & 7) | (((id >> 3) & 3) << 3);   // id%8 == bh%8 -> per-bh XCD affinity
    const int band = 31 - (id >> 5);                    // LPT: heavy bands first
    const int b_ = bh >> 4, h = bh & 15;
    const int t = threadIdx.x;
    const int lane = t & 63, w = t >> 6;
    const int hw = w & 1;          // row half
    const int jh = w >> 1;         // j half (== t>>7, same partition as staging group)
    const int lr = lane & 15, quad = lane >> 4, q8 = quad << 3;

    __shared__ __align__(16) bfu Ks[2][2][64 * 64];   // [jh][buf] 32 KB
    __shared__ __align__(16) bfu Vs[2][2][64 * 64];   // [jh][buf] 32 KB

    const int n  = band + 1;
    const int n0 = (n + 1) >> 1;
    const int nj = (jh == 0) ? n0 : (n - n0);   // my half's iteration count
    const int jb = (jh == 0) ? 0 : n0;          // my half's base j-tile

    const int tl = t & 127;                      // staging lane within half-group
    const int r0 = band * 64 + hw * 32;

    const bfu* kbase = kp + (size_t)bh * LL * DK;
    const bfu* vbase = vtp + (size_t)bh * DK * LL;

    // Q B-frags (pre-scaled by 0.125*log2e via Wq): n=lr -> Q row, k = quad*8+j -> d
    bf16x8 aq[2][2];
    for (int mt = 0; mt < 2; mt++)
        for (int kx = 0; kx < 2; kx++)
            aq[mt][kx] = *(const bf16x8*)&qp[((size_t)bh * LL + r0 + mt * 16 + lr) * DK + kx * 32 + q8];

    f32x4 o[2][4];
    for (int mt = 0; mt < 2; mt++)
        for (int nf = 0; nf < 4; nf++) o[mt][nf] = (f32x4){0.f, 0.f, 0.f, 0.f};
    float lsum[2] = {0.f, 0.f};

    // prologue: each half-group stages its first tile (jh=1 may have none)
    if (nj > 0) {
        for (int it = 0; it < 4; ++it) {
            int c = tl + it * 128;
            int r = c >> 3, gx = (c & 7) ^ (r & 7);
            gload_lds16(&kbase[(size_t)(jb * 64 + r) * DK + gx * 8], &Ks[jh][0][(size_t)c * 8]);
            gload_lds16(&vbase[(size_t)r * LL + jb * 64 + gx * 8], &Vs[jh][0][(size_t)c * 8]);
        }
    }
    __syncthreads();

    for (int i = 0; i < n0; ++i) {
        const int buf = i & 1;
        if (i + 1 < nj) {   // prefetch my half's next tile (drained at barrier)
            const int nb = buf ^ 1, jn = jb + i + 1;
            for (int it = 0; it < 4; ++it) {
                int c = tl + it * 128;
                int r = c >> 3, gx = (c & 7) ^ (r & 7);
                gload_lds16(&kbase[(size_t)(jn * 64 + r) * DK + gx * 8], &Ks[jh][nb][(size_t)c * 8]);
                gload_lds16(&vbase[(size_t)r * LL + jn * 64 + gx * 8], &Vs[jh][nb][(size_t)c * 8]);
            }
        }
        if (i < nj) {
            const int j = jb + i;
            const bfu* Kt = Ks[jh][buf];
            const bfu* Vt = Vs[jh][buf];
            // --- S^T = K Q^T : A=K-frag (rows=k), B=Q-frag (cols=m) ---
            f32x4 sv[4][2];   // [kt][mt]
            for (int kt = 0; kt < 4; kt++)
                for (int mt = 0; mt < 2; mt++) sv[kt][mt] = (f32x4){0.f, 0.f, 0.f, 0.f};
            for (int kx = 0; kx < 2; kx++)
                for (int kt = 0; kt < 4; kt++) {
                    bf16x8 ak = *(const bf16x8*)&Kt[swz(kt * 16 + lr, kx * 4 + quad)];
                    for (int mt = 0; mt < 2; mt++)
                        sv[kt][mt] = __builtin_amdgcn_mfma_f32_16x16x32_bf16(ak, aq[mt][kx], sv[kt][mt], 0, 0, 0);
                }
            // --- causal mask on the diagonal tile: valid iff k <= m ---
            if (j == band) {
                const int mb = r0 & 63;
                for (int kt = 0; kt < 4; kt++)
                    for (int mt = 0; mt < 2; mt++)
                        for (int r = 0; r < 4; r++) {
                            int kl = kt * 16 + quad * 4 + r;
                            int ml = mb + mt * 16 + lr;
                            if (kl > ml) sv[kt][mt][r] = -1e9f;
                        }
            }
            // --- p = exp2(s), per-lane partial l ---
            for (int kt = 0; kt < 4; kt++)
                for (int mt = 0; mt < 2; mt++)
                    for (int r = 0; r < 4; r++) {
                        float e = __builtin_amdgcn_exp2f(sv[kt][mt][r]);
                        sv[kt][mt][r] = e;
                        lsum[mt] += e;
                    }
            // --- O^T += V^T P^T : A=V-frag (pi-permuted cols), B=P-frag from registers ---
            for (int kx = 0; kx < 2; kx++) {
                BF8 pf[2];
                for (int mt = 0; mt < 2; mt++) {
                    pf[mt].w[0] = pktrunc(sv[kx][mt][1], sv[kx][mt][0]);
                    pf[mt].w[1] = pktrunc(sv[kx][mt][3], sv[kx][mt][2]);
                    pf[mt].w[2] = pktrunc(sv[2 + kx][mt][1], sv[2 + kx][mt][0]);
                    pf[mt].w[3] = pktrunc(sv[2 + kx][mt][3], sv[2 + kx][mt][2]);
                }
                for (int nf = 0; nf < 4; nf++) {
                    bf16x8 av = *(const bf16x8*)&Vt[swz(nf * 16 + lr, kx * 4 + quad)];
                    for (int mt = 0; mt < 2; mt++)
                        o[mt][nf] = __builtin_amdgcn_mfma_f32_16x16x32_bf16(av, pf[mt].v, o[mt][nf], 0, 0, 0);
                }
            }
        }
        __syncthreads();   // drains prefetch + protects buffer reuse
    }

    // ---- combine the two j-halves through LDS (overlaying Ks/Vs; loop ended with barrier) ----
    float* Of = (float*)&Ks[0][0][0];   // 128 rows x 33 floats (stride 33 kills pow2 banks)
    float* Lf = (float*)&Vs[0][0][0];   // 128 x 2 floats
    const int ci = hw * 64 + lane;
    if (jh == 1) {
        float* dst = Of + ci * 33;
        for (int mt = 0; mt < 2; mt++)
            for (int nf = 0; nf < 4; nf++)
                for (int r = 0; r < 4; r++)
                    dst[mt * 16 + nf * 4 + r] = o[mt][nf][r];
        Lf[ci * 2 + 0] = lsum[0];
        Lf[ci * 2 + 1] = lsum[1];
    }
    __syncthreads();
    if (jh == 0) {
        const float* src = Of + ci * 33;
        for (int mt = 0; mt < 2; mt++)
            for (int nf = 0; nf < 4; nf++)
                for (int r = 0; r < 4; r++)
                    o[mt][nf][r] += src[mt * 16 + nf * 4 + r];
        lsum[0] += Lf[ci * 2 + 0];
        lsum[1] += Lf[ci * 2 + 1];

        // epilogue: l = quad-reduce(lsum); O^T cols = m = lr matches l's lane ownership
        for (int mt = 0; mt < 2; mt++) {
            float l = lsum[mt];
            l += __shfl_xor(l, 16);
            l += __shfl_xor(l, 32);
            float rinv = 1.0f / l;
            for (int nf = 0; nf < 4; nf++) {
                uint32_t w0 = ((uint32_t)f2bf(o[mt][nf][1] * rinv) << 16) | f2bf(o[mt][nf][0] * rinv);
                uint32_t w1 = ((uint32_t)f2bf(o[mt][nf][3] * rinv) << 16) | f2bf(o[mt][nf][2] * rinv);
                uint2 pk2 = {w0, w1};
                // attn[b, l=r0+mt*16+lr, h*64 + nf*16 + quad*4 + {0..3}]
                *(uint2*)&attn[((size_t)(b_ * LL + r0 + mt * 16 + lr)) * D_MODEL + h * DK + nf * 16 + quad * 4] = pk2;
            }
        }
    }
}

// ---------------- output GEMM: attn bf16 (gload_lds) x Wo fp32 (pipelined register convert) ----
#define OBM 128
#define OBN 64

__global__ __launch_bounds__(256, 2) void gemm_out(
    const bfu* __restrict__ A, const float* __restrict__ B,
    const float* __restrict__ bias, float* __restrict__ out)
{
    __shared__ __align__(16) bfu As[OBM * 64];   // 16 KB
    __shared__ __align__(16) bfu Bs[OBN * 64];   // 8 KB

    const int t = threadIdx.x;
    const int lane = t & 63, w = t >> 6;
    const int tm = blockIdx.y * OBM, tn = blockIdx.x * OBN;
    const int lr = lane & 15, quad = lane >> 4;

    int brow[2], bcol[2];
    for (int it = 0; it < 2; ++it) {
        int c = t + it * 256;
        brow[it] = c >> 3;
        bcol[it] = ((c & 7) ^ ((c >> 3) & 7)) * 8;
    }

    f32x4 acc[2][4];
    for (int i = 0; i < 2; i++) for (int j = 0; j < 4; j++) acc[i][j] = (f32x4){0.f, 0.f, 0.f, 0.f};

    // prologue: B tile 0 into regs
    float4 rb[2][2];
    for (int it = 0; it < 2; ++it) {
        const float4* pb = (const float4*)&B[(size_t)(tn + brow[it]) * 1024 + 0 + bcol[it]];
        rb[it][0] = pb[0]; rb[it][1] = pb[1];
    }

    for (int kt = 0; kt < 1024; kt += 64) {
        if (kt) __syncthreads();
        // convert current B regs -> LDS; stage A via async gload_lds
        for (int it = 0; it < 2; ++it)
            *(uint4*)&Bs[(size_t)(t + it * 256) * 8] = pack8(rb[it][0], rb[it][1], 1.0f);
        for (int it = 0; it < 4; ++it) {
            int c = t + it * 256;
            int row = c >> 3, gx = (c & 7) ^ (row & 7);
            gload_lds16(&A[(size_t)(tm + row) * 1024 + kt + gx * 8], &As[(size_t)c * 8]);
        }
        // prefetch next B tile into regs (wait lands after MFMA below)
        if (kt + 64 < 1024) {
            for (int it = 0; it < 2; ++it) {
                const float4* pb = (const float4*)&B[(size_t)(tn + brow[it]) * 1024 + kt + 64 + bcol[it]];
                rb[it][0] = pb[0]; rb[it][1] = pb[1];
            }
        }
        __syncthreads();
        for (int kx = 0; kx < 2; kx++) {
            bf16x8 a[2], b[4];
            for (int mt = 0; mt < 2; mt++)
                a[mt] = *(const bf16x8*)&As[swz(w * 32 + mt * 16 + lr, kx * 4 + quad)];
            for (int nt = 0; nt < 4; nt++)
                b[nt] = *(const bf16x8*)&Bs[swz(nt * 16 + lr, kx * 4 + quad)];
            for (int mt = 0; mt < 2; mt++)
                for (int nt = 0; nt < 4; nt++)
                    acc[mt][nt] = __builtin_amdgcn_mfma_f32_16x16x32_bf16(a[mt], b[nt], acc[mt][nt], 0, 0, 0);
        }
    }

    for (int mt = 0; mt < 2; mt++)
        for (int nt = 0; nt < 4; nt++)
            for (int r = 0; r < 4; r++) {
                int m = tm + w * 32 + mt * 16 + quad * 4 + r;
                int n = tn + nt * 16 + lr;
                out[(size_t)m * D_MODEL + n] = acc[mt][nt][r] + bias[n];
            }
}

// ---------------- launch (3 kernels; cvt fused into the GEMM staging, pipelined) ----------------
extern "C" void kernel_launch(void* const* d_in, const int* in_sizes, int n_in,
                              void* d_out, int out_size, void* d_ws, size_t ws_size,
                              hipStream_t stream) {
    const float* Q  = (const float*)d_in[0];
    const float* K  = (const float*)d_in[1];
    const float* V  = (const float*)d_in[2];
    // d_in[3] = causal mask (tril) — hardcoded in attn_kernel
    const float* Wq = (const float*)d_in[4];
    const float* bq = (const float*)d_in[5];
    const float* Wk = (const float*)d_in[6];
    const float* bk = (const float*)d_in[7];
    const float* Wv = (const float*)d_in[8];
    const float* bv = (const float*)d_in[9];
    const float* Wo = (const float*)d_in[10];
    const float* bo = (const float*)d_in[11];
    float* out = (float*)d_out;

    char* ws = (char*)d_ws;
    bfu* qp  = (bfu*)(ws + ((size_t)0  << 20));  // 8 MB [B,NH,L,DK]  (Wq pre-scaled)
    bfu* kp  = (bfu*)(ws + ((size_t)8  << 20));  // 8 MB [B,NH,L,DK]
    bfu* vt  = (bfu*)(ws + ((size_t)16 << 20));  // 8 MB [B,NH,DK,L] pi-permuted columns
    bfu* attn = (bfu*)(ws + ((size_t)24 << 20)); // 8 MB [B,L,D]

    gemm_proj<<<768, 256, 0, stream>>>(Q, K, V, Wq, Wk, Wv,
                                       bq, bk, bv, qp, kp, vt);

    attn_kernel<<<dim3(1024), 256, 0, stream>>>(qp, kp, vt, attn);

    gemm_out<<<dim3(16, 32), 256, 0, stream>>>(attn, Wo, bo, out);
}